// Round 5
// baseline (180.135 us; speedup 1.0000x reference)
//
#include <hip/hip_runtime.h>

#define KHOPS  8
#define BS     1024            // scatter/gather/merge block size
#define MAXL   50176           // max links (LDS tables sized for this)
#define HWORDS (MAXL / 2)      // 25088 u32 words = 100352 B (u16-pair histogram)
#define GRID   256             // scatter grid: 1 block/CU
#define NXCD   8               // merge groups == XCD count
#define RPQ    (GRID / NXCD)   // replicas per merge group = 32
#define TSCALE  2048.0f        // traffic deposit fixed-point scale (Q11)
#define XSCALE  131072.0f      // X_l fixed-point scale (Q17; X < 0.5 guaranteed)

typedef unsigned char  u8;
typedef unsigned short u16;
typedef unsigned int   u32;
typedef int   v4i __attribute__((ext_vector_type(4)));
typedef float v4f __attribute__((ext_vector_type(4)));
typedef u32   v4u __attribute__((ext_vector_type(4)));
typedef u32   v2u __attribute__((ext_vector_type(2)));

// ---------------------------------------------------------------------------
// deposit helper: packed u16-pair histogram, ds_add_u32
// ---------------------------------------------------------------------------
__device__ __forceinline__ void deposit(u32* h, u32 link, float t) {
    atomicAdd(&h[link >> 1], __float2uint_rn(t * TSCALE) << ((link & 1) << 4));
}

// ---------------------------------------------------------------------------
// scatter, iteration 1 (fused convert): reads raw int edges + P with NT hint
// (read-once; keep them out of L2 so Trep/e16 stay resident), converts to
// packed u16 (writes e16 for later passes) and compact A; bp == 0.5 constant.
// ---------------------------------------------------------------------------
__global__ __launch_bounds__(BS) void scatter_first(
        const float* __restrict__ P,         // (n_paths,3)
        const int*   __restrict__ pl_edges,  // (KHOPS,n_paths)
        u16*   __restrict__ e16,             // out: packed link ids
        float* __restrict__ A,               // out: compact traffic source
        u32*   __restrict__ Trep,            // [GRID][nwords]
        int n_paths, int nwords) {
    __shared__ u32 h[HWORDS];
    const int tid = threadIdx.x;
    const int nthreads = gridDim.x * BS;

    for (int i = tid; i < (HWORDS >> 2); i += BS)
        ((uint4*)h)[i] = make_uint4(0u, 0u, 0u, 0u);
    __syncthreads();

    for (int p = (blockIdx.x * BS + tid) * 4; p < n_paths; p += 4 * nthreads) {
        uint2 ep[KHOPS];
#pragma unroll
        for (int k = 0; k < KHOPS; ++k) {
            v4i e4 = __builtin_nontemporal_load((const v4i*)&pl_edges[k * n_paths + p]);
            ep[k].x = (u32)(e4[0] - n_paths) | ((u32)(e4[1] - n_paths) << 16);
            ep[k].y = (u32)(e4[2] - n_paths) | ((u32)(e4[3] - n_paths) << 16);
            *(uint2*)&e16[k * n_paths + p] = ep[k];               // cacheable: reused
        }
        v4f q0 = __builtin_nontemporal_load((const v4f*)&P[3 * p]);      // A = P[:,1]
        v4f q1 = __builtin_nontemporal_load((const v4f*)&P[3 * p + 4]);
        v4f q2 = __builtin_nontemporal_load((const v4f*)&P[3 * p + 8]);
        float t0 = q0[1], t1 = q1[0], t2 = q1[3], t3 = q2[2];
        *(float4*)&A[p] = make_float4(t0, t1, t2, t3);
#pragma unroll
        for (int k = 0; k < KHOPS; ++k) {
            deposit(h, ep[k].x & 0xffffu, t0);
            deposit(h, ep[k].x >> 16,     t1);
            deposit(h, ep[k].y & 0xffffu, t2);
            deposit(h, ep[k].y >> 16,     t3);
            t0 *= 0.5f; t1 *= 0.5f; t2 *= 0.5f; t3 *= 0.5f;
        }
    }
    __syncthreads();

    // flush with ds_read_b128 + global_store_dwordx4 (cacheable: merge re-reads)
    u32* Tmine = Trep + (size_t)blockIdx.x * nwords;
    const int nw4 = nwords >> 2;
    for (int i = tid; i < nw4; i += BS)
        ((uint4*)Tmine)[i] = ((const uint4*)h)[i];
    for (int i = (nw4 << 2) + tid; i < nwords; i += BS) Tmine[i] = h[i];
}

// ---------------------------------------------------------------------------
// scatter, iterations 2+: bp table in LDS as u8 Q8 (50 KB) + full histogram
// (100 KB) = 147 KB -> single chunk, 1 block/CU.
// ---------------------------------------------------------------------------
__global__ __launch_bounds__(BS) void scatter_rest(
        const float* __restrict__ A,
        const u16*   __restrict__ e16,
        const u8*    __restrict__ bpq,       // (n_links) Q8, 16B-aligned
        u32*         __restrict__ Trep,
        int n_paths, int n_links, int nwords) {
    __shared__ u8  bpl[MAXL];                // 50176 B
    __shared__ u32 h[HWORDS];                // 100352 B
    const int tid = threadIdx.x;
    const int nthreads = gridDim.x * BS;

    const int nb16 = n_links >> 4;
    for (int i = tid; i < nb16; i += BS)
        ((uint4*)bpl)[i] = ((const uint4*)bpq)[i];
    for (int i = (nb16 << 4) + tid; i < n_links; i += BS) bpl[i] = bpq[i];
    for (int i = tid; i < (HWORDS >> 2); i += BS)
        ((uint4*)h)[i] = make_uint4(0u, 0u, 0u, 0u);
    __syncthreads();

    for (int p = (blockIdx.x * BS + tid) * 4; p < n_paths; p += 4 * nthreads) {
        uint2 ep[KHOPS];
#pragma unroll
        for (int k = 0; k < KHOPS; ++k)
            ep[k] = *(const uint2*)&e16[k * n_paths + p];   // cacheable: reused
        float4 a = *(const float4*)&A[p];
        float t0 = a.x, t1 = a.y, t2 = a.z, t3 = a.w;
#pragma unroll
        for (int k = 0; k < KHOPS; ++k) {
            u32 l0 = ep[k].x & 0xffffu, l1 = ep[k].x >> 16;
            u32 l2 = ep[k].y & 0xffffu, l3 = ep[k].y >> 16;
            deposit(h, l0, t0);
            deposit(h, l1, t1);
            deposit(h, l2, t2);
            deposit(h, l3, t3);
            t0 *= (float)(256 - (int)bpl[l0]) * (1.0f / 256.0f);
            t1 *= (float)(256 - (int)bpl[l1]) * (1.0f / 256.0f);
            t2 *= (float)(256 - (int)bpl[l2]) * (1.0f / 256.0f);
            t3 *= (float)(256 - (int)bpl[l3]) * (1.0f / 256.0f);
        }
    }
    __syncthreads();

    u32* Tmine = Trep + (size_t)blockIdx.x * nwords;
    const int nw4 = nwords >> 2;
    for (int i = tid; i < nw4; i += BS)
        ((uint4*)Tmine)[i] = ((const uint4*)h)[i];
    for (int i = (nw4 << 2) + tid; i < nwords; i += BS) Tmine[i] = h[i];
}

// ---------------------------------------------------------------------------
// merge: group q sums replicas r == q (mod 8). Replica r was written by
// scatter block r on XCD r%8; merge block has q = blockIdx.x & 7 -> same XCD
// -> L2-local reads (32 x 100 KB = 3.2 MB fits the 4 MB XCD L2).
// uint4 loads (16 B/lane, NT: lines are dead after this read) + 2x uint4
// stores. Per-link j-loop order identical -> bit-identical u32 sums.
// ---------------------------------------------------------------------------
__global__ __launch_bounds__(BS) void merge_kernel(
        const u32* __restrict__ Trep,
        u32* __restrict__ partial,           // [NXCD][n_links]
        int n_links, int nwords) {
    const int q  = blockIdx.x & (NXCD - 1);
    const int p4 = (blockIdx.x >> 3) * BS + threadIdx.x;   // word-quad index
    const int nquads = nwords >> 2;

    if (p4 < nquads) {
        u32 s0 = 0, s1 = 0, s2 = 0, s3 = 0, s4 = 0, s5 = 0, s6 = 0, s7 = 0;
#pragma unroll 4
        for (int j = 0; j < RPQ; ++j) {
            v4u v = __builtin_nontemporal_load(
                (const v4u*)&Trep[(size_t)(q + NXCD * j) * nwords + 4 * p4]);
            s0 += v[0] & 0xffffu;  s1 += v[0] >> 16;
            s2 += v[1] & 0xffffu;  s3 += v[1] >> 16;
            s4 += v[2] & 0xffffu;  s5 += v[2] >> 16;
            s6 += v[3] & 0xffffu;  s7 += v[3] >> 16;
        }
        u32* dst = &partial[(size_t)q * n_links + 8 * p4];
        *(uint4*)dst       = make_uint4(s0, s1, s2, s3);
        *(uint4*)(dst + 4) = make_uint4(s4, s5, s6, s7);
    }
    // tail words (nwords % 4 != 0): scalar, handled by first block of group q
    if ((blockIdx.x >> 3) == 0) {
        for (int w = (nquads << 2) + threadIdx.x; w < nwords; w += BS) {
            u32 slo = 0, shi = 0;
            for (int j = 0; j < RPQ; ++j) {
                u32 v = Trep[(size_t)(q + NXCD * j) * nwords + w];
                slo += v & 0xffffu;  shi += v >> 16;
            }
            partial[(size_t)q * n_links + 2 * w] = slo;
            if (2 * w + 1 < n_links)
                partial[(size_t)q * n_links + 2 * w + 1] = shi;
        }
    }
}

// ---------------------------------------------------------------------------
// link update: T = (sum of 8 integer partials)/TSCALE; rho; writes bp (Q8)
// on early iterations, full epilogue (outputs + xq) on the last.
// ---------------------------------------------------------------------------
__global__ void link_update_kernel(const float* __restrict__ L,
                                   const u32*   __restrict__ partial,
                                   u8*          __restrict__ bpq,
                                   u16*         __restrict__ xq,
                                   float*       __restrict__ out_links,
                                   int n_links, int last) {
    int l = blockIdx.x * blockDim.x + threadIdx.x;
    if (l >= n_links) return;
    u32 s = 0;
#pragma unroll
    for (int q = 0; q < NXCD; ++q)
        s += partial[(size_t)q * n_links + l];
    float T   = (float)s * (1.0f / TSCALE);
    float cap = L[l] * (1.0f / 1000.0f);
    float rho = T / cap;
    float r2 = rho * rho, r4 = r2 * r2, r8 = r4 * r4, r16 = r8 * r8;
    float r32 = r16 * r16, r33 = r32 * rho;
    if (!last) {
        float bp = (1.0f - rho) * r32 / (1.0f - r33 + 1e-8f);
        u32 b = __float2uint_rn(bp * 256.0f);
        bpq[l] = (u8)(b > 255u ? 255u : b);
    } else {
        float pi0 = (1.0f - rho) / (1.0f - r33);     // no epsilon (ref)
        float S = 1.0f, rp = 1.0f;
#pragma unroll
        for (int m = 1; m <= 32; ++m) { rp *= rho; S += (float)m * rp; }
        float Lq = pi0 * S * (1.0f / 32.0f);
        float X  = Lq * 32000.0f / L[l];
        u32 xf = __float2uint_rn(X * XSCALE);
        xq[l] = (u16)(xf > 65535u ? 65535u : xf);
        out_links[3 * l + 0] = Lq;
        out_links[3 * l + 1] = rho;
        out_links[3 * l + 2] = pi0 * r32;
    }
}

// ---------------------------------------------------------------------------
// gather: X_l table in LDS (Q17 u16); integer per-path sum, 4 paths/thread.
// e16 loads NT (last use); res store NT (never re-read).
// ---------------------------------------------------------------------------
__global__ __launch_bounds__(BS) void gather_kernel(
        const u16* __restrict__ e16,
        const u16* __restrict__ xq,          // 16B-aligned
        float*     __restrict__ res,
        int n_paths, int n_links) {
    __shared__ u16 xl[MAXL];
    const int tid = threadIdx.x;
    const int nx8 = n_links >> 3;            // 8 u16 per uint4
    for (int i = tid; i < nx8; i += BS)
        ((uint4*)xl)[i] = ((const uint4*)xq)[i];
    for (int i = (nx8 << 3) + tid; i < n_links; i += BS) xl[i] = xq[i];
    __syncthreads();

    const int nthreads = gridDim.x * BS;
    for (int p = (blockIdx.x * BS + tid) * 4; p < n_paths; p += 4 * nthreads) {
        u32 s0 = 0, s1 = 0, s2 = 0, s3 = 0;
#pragma unroll
        for (int k = 0; k < KHOPS; ++k) {
            v2u ep = __builtin_nontemporal_load((const v2u*)&e16[k * n_paths + p]);
            s0 += xl[ep[0] & 0xffffu];
            s1 += xl[ep[0] >> 16];
            s2 += xl[ep[1] & 0xffffu];
            s3 += xl[ep[1] >> 16];
        }
        v4f r = { (float)s0 * (1.0f / XSCALE), (float)s1 * (1.0f / XSCALE),
                  (float)s2 * (1.0f / XSCALE), (float)s3 * (1.0f / XSCALE) };
        __builtin_nontemporal_store(r, (v4f*)&res[p]);
    }
}

// ---------------------------------------------------------------------------
extern "C" void kernel_launch(void* const* d_in, const int* in_sizes, int n_in,
                              void* d_out, int out_size, void* d_ws, size_t ws_size,
                              hipStream_t stream) {
    const float* P        = (const float*)d_in[0];   // (n_paths, 3)
    const float* L        = (const float*)d_in[1];   // (n_links, 1)
    const int*   pl_edges = (const int*)d_in[3];     // (KHOPS, n_paths)

    const int n_paths = in_sizes[0] / 3;
    const int n_links = in_sizes[1];
    const int n_edges = KHOPS * n_paths;
    const int nwords  = (n_links + 1) / 2;

    // ws layout: e16 | A | bpq(u8) | xq(u16) | partial (u32 NXCD*nl) | Trep
    char* w = (char*)d_ws;
    u16*   e16 = (u16*)w;                     w += (size_t)n_edges * 2;
    w = (char*)(((size_t)w + 15) & ~15ull);
    float* A   = (float*)w;                   w += (size_t)n_paths * 4;
    u8*    bpq = (u8*)w;                      w += (size_t)n_links;
    w = (char*)(((size_t)w + 15) & ~15ull);
    u16*   xq  = (u16*)w;                     w += (size_t)n_links * 2;
    w = (char*)(((size_t)w + 15) & ~15ull);
    u32* partial = (u32*)w;                   w += (size_t)NXCD * n_links * 4;
    u32* Trep    = (u32*)w;                   // GRID*nwords*4 = 25.6 MB

    float* res       = (float*)d_out;                // (n_paths,)
    float* out_links = res + n_paths;                // (n_links, 3)

    const int bs = 256;
    const int gl = (n_links + bs - 1) / bs;
    const int nquads = nwords >> 2;
    const int gm = NXCD * ((nquads + BS - 1) / BS);  // XCD-aligned merge grid

    for (int it = 0; it < 3; ++it) {
        if (it == 0)
            scatter_first<<<GRID, BS, 0, stream>>>(P, pl_edges, e16, A, Trep,
                                                   n_paths, nwords);
        else
            scatter_rest<<<GRID, BS, 0, stream>>>(A, e16, bpq, Trep,
                                                  n_paths, n_links, nwords);
        merge_kernel<<<gm, BS, 0, stream>>>(Trep, partial, n_links, nwords);
        link_update_kernel<<<gl, bs, 0, stream>>>(L, partial, bpq, xq,
                                                  out_links, n_links,
                                                  it == 2 ? 1 : 0);
    }
    gather_kernel<<<GRID, BS, 0, stream>>>(e16, xq, res, n_paths, n_links);
}

// Round 6
// 175.491 us; speedup vs baseline: 1.0265x; 1.0265x over previous
//
#include <hip/hip_runtime.h>

#define KHOPS  8
#define BS     1024            // scatter/gather/merge block size
#define MAXL   50176           // max links (LDS tables sized for this)
#define HWORDS (MAXL / 2)      // 25088 u32 words = 100352 B (u16-pair histogram)
#define GRID   256             // scatter grid: 1 block/CU
#define NXCD   8               // merge groups == XCD count
#define RPQ    (GRID / NXCD)   // replicas per merge group = 32
#define TSCALE  2048.0f        // traffic deposit fixed-point scale (Q11)
#define XSCALE  131072.0f      // X_l fixed-point scale (Q17; X < 0.5 guaranteed)

typedef unsigned char  u8;
typedef unsigned short u16;
typedef unsigned int   u32;

// ---------------------------------------------------------------------------
// deposit helper: packed u16-pair histogram, ds_add_u32
// ---------------------------------------------------------------------------
__device__ __forceinline__ void deposit(u32* h, u32 link, float t) {
    atomicAdd(&h[link >> 1], __float2uint_rn(t * TSCALE) << ((link & 1) << 4));
}

// ---------------------------------------------------------------------------
// scatter, iteration 1 (fused convert): reads raw int edges + P, converts to
// packed u16 (writes e16 for later passes) and compact A; bp == 0.5 constant.
// Single full-size histogram (100 KB LDS), 4 paths/thread.
// NOTE: plain cached loads everywhere — R5 proved NT hints on anything with a
// downstream reader (esp. Trep in merge) cost +10.7 us by defeating L2.
// ---------------------------------------------------------------------------
__global__ __launch_bounds__(BS) void scatter_first(
        const float* __restrict__ P,         // (n_paths,3)
        const int*   __restrict__ pl_edges,  // (KHOPS,n_paths)
        u16*   __restrict__ e16,             // out: packed link ids
        float* __restrict__ A,               // out: compact traffic source
        u32*   __restrict__ Trep,            // [GRID][nwords]
        int n_paths, int nwords) {
    __shared__ u32 h[HWORDS];
    const int tid = threadIdx.x;
    const int nthreads = gridDim.x * BS;

    // zero histogram with ds_write_b128 (HWORDS % 4 == 0)
    for (int i = tid; i < (HWORDS >> 2); i += BS)
        ((uint4*)h)[i] = make_uint4(0u, 0u, 0u, 0u);
    __syncthreads();

    for (int p = (blockIdx.x * BS + tid) * 4; p < n_paths; p += 4 * nthreads) {
        uint2 ep[KHOPS];
#pragma unroll
        for (int k = 0; k < KHOPS; ++k) {
            int4 e4 = *(const int4*)&pl_edges[k * n_paths + p];   // coalesced
            ep[k].x = (u32)(e4.x - n_paths) | ((u32)(e4.y - n_paths) << 16);
            ep[k].y = (u32)(e4.z - n_paths) | ((u32)(e4.w - n_paths) << 16);
            *(uint2*)&e16[k * n_paths + p] = ep[k];               // coalesced
        }
        float4 q0 = *(const float4*)&P[3 * p];       // A = P[:,1]
        float4 q1 = *(const float4*)&P[3 * p + 4];
        float4 q2 = *(const float4*)&P[3 * p + 8];
        float t0 = q0.y, t1 = q1.x, t2 = q1.w, t3 = q2.z;
        *(float4*)&A[p] = make_float4(t0, t1, t2, t3);
#pragma unroll
        for (int k = 0; k < KHOPS; ++k) {
            deposit(h, ep[k].x & 0xffffu, t0);
            deposit(h, ep[k].x >> 16,     t1);
            deposit(h, ep[k].y & 0xffffu, t2);
            deposit(h, ep[k].y >> 16,     t3);
            t0 *= 0.5f; t1 *= 0.5f; t2 *= 0.5f; t3 *= 0.5f;
        }
    }
    __syncthreads();

    // flush with ds_read_b128 + global_store_dwordx4 (cached: merge re-reads)
    u32* Tmine = Trep + (size_t)blockIdx.x * nwords;
    const int nw4 = nwords >> 2;
    for (int i = tid; i < nw4; i += BS)
        ((uint4*)Tmine)[i] = ((const uint4*)h)[i];
    for (int i = (nw4 << 2) + tid; i < nwords; i += BS) Tmine[i] = h[i];
}

// ---------------------------------------------------------------------------
// scatter, iterations 2+: bp table in LDS as u8 Q8 (50 KB) + full histogram
// (100 KB) = 147 KB -> single chunk, 1 block/CU.
// ---------------------------------------------------------------------------
__global__ __launch_bounds__(BS) void scatter_rest(
        const float* __restrict__ A,
        const u16*   __restrict__ e16,
        const u8*    __restrict__ bpq,       // (n_links) Q8, 16B-aligned
        u32*         __restrict__ Trep,
        int n_paths, int n_links, int nwords) {
    __shared__ u8  bpl[MAXL];                // 50176 B
    __shared__ u32 h[HWORDS];                // 100352 B
    const int tid = threadIdx.x;
    const int nthreads = gridDim.x * BS;

    // stage bp table with 16B loads/stores (tail loop covers remainder)
    const int nb16 = n_links >> 4;
    for (int i = tid; i < nb16; i += BS)
        ((uint4*)bpl)[i] = ((const uint4*)bpq)[i];
    for (int i = (nb16 << 4) + tid; i < n_links; i += BS) bpl[i] = bpq[i];
    for (int i = tid; i < (HWORDS >> 2); i += BS)
        ((uint4*)h)[i] = make_uint4(0u, 0u, 0u, 0u);
    __syncthreads();

    for (int p = (blockIdx.x * BS + tid) * 4; p < n_paths; p += 4 * nthreads) {
        uint2 ep[KHOPS];
#pragma unroll
        for (int k = 0; k < KHOPS; ++k)
            ep[k] = *(const uint2*)&e16[k * n_paths + p];
        float4 a = *(const float4*)&A[p];
        float t0 = a.x, t1 = a.y, t2 = a.z, t3 = a.w;
#pragma unroll
        for (int k = 0; k < KHOPS; ++k) {
            u32 l0 = ep[k].x & 0xffffu, l1 = ep[k].x >> 16;
            u32 l2 = ep[k].y & 0xffffu, l3 = ep[k].y >> 16;
            deposit(h, l0, t0);
            deposit(h, l1, t1);
            deposit(h, l2, t2);
            deposit(h, l3, t3);
            t0 *= (float)(256 - (int)bpl[l0]) * (1.0f / 256.0f);
            t1 *= (float)(256 - (int)bpl[l1]) * (1.0f / 256.0f);
            t2 *= (float)(256 - (int)bpl[l2]) * (1.0f / 256.0f);
            t3 *= (float)(256 - (int)bpl[l3]) * (1.0f / 256.0f);
        }
    }
    __syncthreads();

    u32* Tmine = Trep + (size_t)blockIdx.x * nwords;
    const int nw4 = nwords >> 2;
    for (int i = tid; i < nw4; i += BS)
        ((uint4*)Tmine)[i] = ((const uint4*)h)[i];
    for (int i = (nw4 << 2) + tid; i < nwords; i += BS) Tmine[i] = h[i];
}

// ---------------------------------------------------------------------------
// merge: group q sums replicas r == q (mod 8). Replica r was written by
// scatter block r on XCD r%8; merge block has q = blockIdx.x & 7 -> same XCD
// -> L2-local CACHED reads (32 x 100 KB = 3.2 MB fits the 4 MB XCD L2).
// uint4 loads (16 B/lane, 1 KB/wave-inst) + 2x uint4 stores; per-link j-loop
// order identical -> bit-identical u32 sums.
// ---------------------------------------------------------------------------
__global__ __launch_bounds__(BS) void merge_kernel(
        const u32* __restrict__ Trep,
        u32* __restrict__ partial,           // [NXCD][n_links]
        int n_links, int nwords) {
    const int q  = blockIdx.x & (NXCD - 1);
    const int p4 = (blockIdx.x >> 3) * BS + threadIdx.x;   // word-quad index
    const int nquads = nwords >> 2;

    if (p4 < nquads) {
        u32 s0 = 0, s1 = 0, s2 = 0, s3 = 0, s4 = 0, s5 = 0, s6 = 0, s7 = 0;
#pragma unroll 4
        for (int j = 0; j < RPQ; ++j) {
            uint4 v = *(const uint4*)&Trep[(size_t)(q + NXCD * j) * nwords + 4 * p4];
            s0 += v.x & 0xffffu;  s1 += v.x >> 16;
            s2 += v.y & 0xffffu;  s3 += v.y >> 16;
            s4 += v.z & 0xffffu;  s5 += v.z >> 16;
            s6 += v.w & 0xffffu;  s7 += v.w >> 16;
        }
        u32* dst = &partial[(size_t)q * n_links + 8 * p4];
        *(uint4*)dst       = make_uint4(s0, s1, s2, s3);
        *(uint4*)(dst + 4) = make_uint4(s4, s5, s6, s7);
    }
    // tail words (nwords % 4 != 0): scalar, handled by first block of group q
    if ((blockIdx.x >> 3) == 0) {
        for (int w = (nquads << 2) + threadIdx.x; w < nwords; w += BS) {
            u32 slo = 0, shi = 0;
            for (int j = 0; j < RPQ; ++j) {
                u32 v = Trep[(size_t)(q + NXCD * j) * nwords + w];
                slo += v & 0xffffu;  shi += v >> 16;
            }
            partial[(size_t)q * n_links + 2 * w] = slo;
            if (2 * w + 1 < n_links)
                partial[(size_t)q * n_links + 2 * w + 1] = shi;
        }
    }
}

// ---------------------------------------------------------------------------
// link update: T = (sum of 8 integer partials)/TSCALE; rho; writes bp (Q8)
// on early iterations, full epilogue (outputs + xq) on the last.
// ---------------------------------------------------------------------------
__global__ void link_update_kernel(const float* __restrict__ L,
                                   const u32*   __restrict__ partial,
                                   u8*          __restrict__ bpq,
                                   u16*         __restrict__ xq,
                                   float*       __restrict__ out_links,
                                   int n_links, int last) {
    int l = blockIdx.x * blockDim.x + threadIdx.x;
    if (l >= n_links) return;
    u32 s = 0;
#pragma unroll
    for (int q = 0; q < NXCD; ++q)
        s += partial[(size_t)q * n_links + l];
    float T   = (float)s * (1.0f / TSCALE);
    float cap = L[l] * (1.0f / 1000.0f);
    float rho = T / cap;
    float r2 = rho * rho, r4 = r2 * r2, r8 = r4 * r4, r16 = r8 * r8;
    float r32 = r16 * r16, r33 = r32 * rho;
    if (!last) {
        float bp = (1.0f - rho) * r32 / (1.0f - r33 + 1e-8f);
        u32 b = __float2uint_rn(bp * 256.0f);
        bpq[l] = (u8)(b > 255u ? 255u : b);
    } else {
        float pi0 = (1.0f - rho) / (1.0f - r33);     // no epsilon (ref)
        float S = 1.0f, rp = 1.0f;
#pragma unroll
        for (int m = 1; m <= 32; ++m) { rp *= rho; S += (float)m * rp; }
        float Lq = pi0 * S * (1.0f / 32.0f);
        float X  = Lq * 32000.0f / L[l];
        u32 xf = __float2uint_rn(X * XSCALE);
        xq[l] = (u16)(xf > 65535u ? 65535u : xf);
        out_links[3 * l + 0] = Lq;
        out_links[3 * l + 1] = rho;
        out_links[3 * l + 2] = pi0 * r32;
    }
}

// ---------------------------------------------------------------------------
// gather: X_l table in LDS (Q17 u16); integer per-path sum, 4 paths/thread.
// ---------------------------------------------------------------------------
__global__ __launch_bounds__(BS) void gather_kernel(
        const u16* __restrict__ e16,
        const u16* __restrict__ xq,          // 16B-aligned
        float*     __restrict__ res,
        int n_paths, int n_links) {
    __shared__ u16 xl[MAXL];
    const int tid = threadIdx.x;
    const int nx8 = n_links >> 3;            // 8 u16 per uint4
    for (int i = tid; i < nx8; i += BS)
        ((uint4*)xl)[i] = ((const uint4*)xq)[i];
    for (int i = (nx8 << 3) + tid; i < n_links; i += BS) xl[i] = xq[i];
    __syncthreads();

    const int nthreads = gridDim.x * BS;
    for (int p = (blockIdx.x * BS + tid) * 4; p < n_paths; p += 4 * nthreads) {
        u32 s0 = 0, s1 = 0, s2 = 0, s3 = 0;
#pragma unroll
        for (int k = 0; k < KHOPS; ++k) {
            uint2 ep = *(const uint2*)&e16[k * n_paths + p];
            s0 += xl[ep.x & 0xffffu];
            s1 += xl[ep.x >> 16];
            s2 += xl[ep.y & 0xffffu];
            s3 += xl[ep.y >> 16];
        }
        *(float4*)&res[p] = make_float4((float)s0 * (1.0f / XSCALE),
                                        (float)s1 * (1.0f / XSCALE),
                                        (float)s2 * (1.0f / XSCALE),
                                        (float)s3 * (1.0f / XSCALE));
    }
}

// ---------------------------------------------------------------------------
extern "C" void kernel_launch(void* const* d_in, const int* in_sizes, int n_in,
                              void* d_out, int out_size, void* d_ws, size_t ws_size,
                              hipStream_t stream) {
    const float* P        = (const float*)d_in[0];   // (n_paths, 3)
    const float* L        = (const float*)d_in[1];   // (n_links, 1)
    const int*   pl_edges = (const int*)d_in[3];     // (KHOPS, n_paths)

    const int n_paths = in_sizes[0] / 3;
    const int n_links = in_sizes[1];
    const int n_edges = KHOPS * n_paths;
    const int nwords  = (n_links + 1) / 2;

    // ws layout: e16 | A | bpq(u8) | xq(u16) | partial (u32 NXCD*nl) | Trep
    char* w = (char*)d_ws;
    u16*   e16 = (u16*)w;                     w += (size_t)n_edges * 2;
    w = (char*)(((size_t)w + 15) & ~15ull);
    float* A   = (float*)w;                   w += (size_t)n_paths * 4;
    u8*    bpq = (u8*)w;                      w += (size_t)n_links;
    w = (char*)(((size_t)w + 15) & ~15ull);
    u16*   xq  = (u16*)w;                     w += (size_t)n_links * 2;
    w = (char*)(((size_t)w + 15) & ~15ull);
    u32* partial = (u32*)w;                   w += (size_t)NXCD * n_links * 4;
    u32* Trep    = (u32*)w;                   // GRID*nwords*4 = 25.6 MB

    float* res       = (float*)d_out;                // (n_paths,)
    float* out_links = res + n_paths;                // (n_links, 3)

    const int bs = 256;
    const int gl = (n_links + bs - 1) / bs;
    const int nquads = nwords >> 2;
    const int gm = NXCD * ((nquads + BS - 1) / BS);  // XCD-aligned merge grid

    for (int it = 0; it < 3; ++it) {
        if (it == 0)
            scatter_first<<<GRID, BS, 0, stream>>>(P, pl_edges, e16, A, Trep,
                                                   n_paths, nwords);
        else
            scatter_rest<<<GRID, BS, 0, stream>>>(A, e16, bpq, Trep,
                                                  n_paths, n_links, nwords);
        merge_kernel<<<gm, BS, 0, stream>>>(Trep, partial, n_links, nwords);
        link_update_kernel<<<gl, bs, 0, stream>>>(L, partial, bpq, xq,
                                                  out_links, n_links,
                                                  it == 2 ? 1 : 0);
    }
    gather_kernel<<<GRID, BS, 0, stream>>>(e16, xq, res, n_paths, n_links);
}

// Round 7
// 171.571 us; speedup vs baseline: 1.0499x; 1.0228x over previous
//
#include <hip/hip_runtime.h>

#define KHOPS  8
#define BS     1024            // scatter/gather/merge block size
#define MAXL   50176           // max links (LDS tables sized for this)
#define HWORDS (MAXL / 2)      // 25088 u32 words = 100352 B (u16-pair histogram)
#define GRID   256             // scatter grid: 1 block/CU
#define NXCD   8               // merge groups == XCD count
#define RPQ    (GRID / NXCD)   // replicas per merge group = 32
#define TSCALE  2048.0f        // traffic deposit fixed-point scale (Q11)
#define XSCALE  131072.0f      // X_l fixed-point scale (Q17; X < 0.5 guaranteed)

typedef unsigned char  u8;
typedef unsigned short u16;
typedef unsigned int   u32;

// ---------------------------------------------------------------------------
// deposit helper: packed u16-pair histogram, ds_add_u32
// ---------------------------------------------------------------------------
__device__ __forceinline__ void deposit(u32* h, u32 link, float t) {
    atomicAdd(&h[link >> 1], __float2uint_rn(t * TSCALE) << ((link & 1) << 4));
}

// ---------------------------------------------------------------------------
// scatter, iteration 1 (fused convert): reads raw int edges + P, converts to
// packed u16 (writes e16 for later passes) and compact A; bp == 0.5 constant.
// Single full-size histogram (100 KB LDS), 4 paths/thread.
// NOTE: plain cached loads everywhere — R5 proved NT hints on anything with a
// downstream reader (esp. Trep in merge) cost +10.7 us by defeating L2.
// ---------------------------------------------------------------------------
__global__ __launch_bounds__(BS) void scatter_first(
        const float* __restrict__ P,         // (n_paths,3)
        const int*   __restrict__ pl_edges,  // (KHOPS,n_paths)
        u16*   __restrict__ e16,             // out: packed link ids
        float* __restrict__ A,               // out: compact traffic source
        u32*   __restrict__ Trep,            // [GRID][nwords]
        int n_paths, int nwords) {
    __shared__ u32 h[HWORDS];
    const int tid = threadIdx.x;
    const int nthreads = gridDim.x * BS;

    // zero histogram with ds_write_b128 (HWORDS % 4 == 0)
    for (int i = tid; i < (HWORDS >> 2); i += BS)
        ((uint4*)h)[i] = make_uint4(0u, 0u, 0u, 0u);
    __syncthreads();

    for (int p = (blockIdx.x * BS + tid) * 4; p < n_paths; p += 4 * nthreads) {
        uint2 ep[KHOPS];
#pragma unroll
        for (int k = 0; k < KHOPS; ++k) {
            int4 e4 = *(const int4*)&pl_edges[k * n_paths + p];   // coalesced
            ep[k].x = (u32)(e4.x - n_paths) | ((u32)(e4.y - n_paths) << 16);
            ep[k].y = (u32)(e4.z - n_paths) | ((u32)(e4.w - n_paths) << 16);
            *(uint2*)&e16[k * n_paths + p] = ep[k];               // coalesced
        }
        float4 q0 = *(const float4*)&P[3 * p];       // A = P[:,1]
        float4 q1 = *(const float4*)&P[3 * p + 4];
        float4 q2 = *(const float4*)&P[3 * p + 8];
        float t0 = q0.y, t1 = q1.x, t2 = q1.w, t3 = q2.z;
        *(float4*)&A[p] = make_float4(t0, t1, t2, t3);
#pragma unroll
        for (int k = 0; k < KHOPS; ++k) {
            deposit(h, ep[k].x & 0xffffu, t0);
            deposit(h, ep[k].x >> 16,     t1);
            deposit(h, ep[k].y & 0xffffu, t2);
            deposit(h, ep[k].y >> 16,     t3);
            t0 *= 0.5f; t1 *= 0.5f; t2 *= 0.5f; t3 *= 0.5f;
        }
    }
    __syncthreads();

    // flush with ds_read_b128 + global_store_dwordx4 (cached: merge re-reads)
    u32* Tmine = Trep + (size_t)blockIdx.x * nwords;
    const int nw4 = nwords >> 2;
    for (int i = tid; i < nw4; i += BS)
        ((uint4*)Tmine)[i] = ((const uint4*)h)[i];
    for (int i = (nw4 << 2) + tid; i < nwords; i += BS) Tmine[i] = h[i];
}

// ---------------------------------------------------------------------------
// scatter, iterations 2+: bp table in LDS as u8 Q8 (50 KB) + full histogram
// (100 KB) = 147 KB -> single chunk, 1 block/CU.
// ---------------------------------------------------------------------------
__global__ __launch_bounds__(BS) void scatter_rest(
        const float* __restrict__ A,
        const u16*   __restrict__ e16,
        const u8*    __restrict__ bpq,       // (n_links) Q8, 16B-aligned
        u32*         __restrict__ Trep,
        int n_paths, int n_links, int nwords) {
    __shared__ u8  bpl[MAXL];                // 50176 B
    __shared__ u32 h[HWORDS];                // 100352 B
    const int tid = threadIdx.x;
    const int nthreads = gridDim.x * BS;

    // stage bp table with 16B loads/stores (tail loop covers remainder)
    const int nb16 = n_links >> 4;
    for (int i = tid; i < nb16; i += BS)
        ((uint4*)bpl)[i] = ((const uint4*)bpq)[i];
    for (int i = (nb16 << 4) + tid; i < n_links; i += BS) bpl[i] = bpq[i];
    for (int i = tid; i < (HWORDS >> 2); i += BS)
        ((uint4*)h)[i] = make_uint4(0u, 0u, 0u, 0u);
    __syncthreads();

    for (int p = (blockIdx.x * BS + tid) * 4; p < n_paths; p += 4 * nthreads) {
        uint2 ep[KHOPS];
#pragma unroll
        for (int k = 0; k < KHOPS; ++k)
            ep[k] = *(const uint2*)&e16[k * n_paths + p];
        float4 a = *(const float4*)&A[p];
        float t0 = a.x, t1 = a.y, t2 = a.z, t3 = a.w;
#pragma unroll
        for (int k = 0; k < KHOPS; ++k) {
            u32 l0 = ep[k].x & 0xffffu, l1 = ep[k].x >> 16;
            u32 l2 = ep[k].y & 0xffffu, l3 = ep[k].y >> 16;
            deposit(h, l0, t0);
            deposit(h, l1, t1);
            deposit(h, l2, t2);
            deposit(h, l3, t3);
            t0 *= (float)(256 - (int)bpl[l0]) * (1.0f / 256.0f);
            t1 *= (float)(256 - (int)bpl[l1]) * (1.0f / 256.0f);
            t2 *= (float)(256 - (int)bpl[l2]) * (1.0f / 256.0f);
            t3 *= (float)(256 - (int)bpl[l3]) * (1.0f / 256.0f);
        }
    }
    __syncthreads();

    u32* Tmine = Trep + (size_t)blockIdx.x * nwords;
    const int nw4 = nwords >> 2;
    for (int i = tid; i < nw4; i += BS)
        ((uint4*)Tmine)[i] = ((const uint4*)h)[i];
    for (int i = (nw4 << 2) + tid; i < nwords; i += BS) Tmine[i] = h[i];
}

// ---------------------------------------------------------------------------
// merge: group q sums replicas r == q (mod 8). Replica r was written by
// scatter block r on XCD r%8; merge block has q = blockIdx.x & 7 -> same XCD
// -> L2-local reads (32 x 100 KB = 3.2 MB fits the 4 MB XCD L2).
// uint2 loads (8 B/lane, 512 B/wave-inst, lanes contiguous) + single dense
// uint4 store (16 B/lane stride — R6 showed wider strided stores regress).
// Bit-identical u32 arithmetic to the verified scalar merge.
// ---------------------------------------------------------------------------
__global__ __launch_bounds__(BS) void merge_kernel(
        const u32* __restrict__ Trep,
        u32* __restrict__ partial,           // [NXCD][n_links]
        int n_links, int nwords) {
    const int q  = blockIdx.x & (NXCD - 1);
    const int p2 = (blockIdx.x >> 3) * BS + threadIdx.x;   // word-pair index
    const int npairs = nwords >> 1;
    if (p2 >= npairs) return;
    u32 s0 = 0, s1 = 0, s2 = 0, s3 = 0;    // lo0, hi0, lo1, hi1
#pragma unroll 4
    for (int j = 0; j < RPQ; ++j) {
        uint2 v = *(const uint2*)&Trep[(size_t)(q + NXCD * j) * nwords + 2 * p2];
        s0 += v.x & 0xffffu;  s1 += v.x >> 16;
        s2 += v.y & 0xffffu;  s3 += v.y >> 16;
    }
    *(uint4*)&partial[(size_t)q * n_links + 4 * p2] = make_uint4(s0, s1, s2, s3);
}

// ---------------------------------------------------------------------------
// link update: T = (sum of 8 integer partials)/TSCALE; rho; writes bp (Q8)
// on early iterations, full epilogue (outputs + xq) on the last.
// ---------------------------------------------------------------------------
__global__ void link_update_kernel(const float* __restrict__ L,
                                   const u32*   __restrict__ partial,
                                   u8*          __restrict__ bpq,
                                   u16*         __restrict__ xq,
                                   float*       __restrict__ out_links,
                                   int n_links, int last) {
    int l = blockIdx.x * blockDim.x + threadIdx.x;
    if (l >= n_links) return;
    u32 s = 0;
#pragma unroll
    for (int q = 0; q < NXCD; ++q)
        s += partial[(size_t)q * n_links + l];
    float T   = (float)s * (1.0f / TSCALE);
    float cap = L[l] * (1.0f / 1000.0f);
    float rho = T / cap;
    float r2 = rho * rho, r4 = r2 * r2, r8 = r4 * r4, r16 = r8 * r8;
    float r32 = r16 * r16, r33 = r32 * rho;
    if (!last) {
        float bp = (1.0f - rho) * r32 / (1.0f - r33 + 1e-8f);
        u32 b = __float2uint_rn(bp * 256.0f);
        bpq[l] = (u8)(b > 255u ? 255u : b);
    } else {
        float pi0 = (1.0f - rho) / (1.0f - r33);     // no epsilon (ref)
        float S = 1.0f, rp = 1.0f;
#pragma unroll
        for (int m = 1; m <= 32; ++m) { rp *= rho; S += (float)m * rp; }
        float Lq = pi0 * S * (1.0f / 32.0f);
        float X  = Lq * 32000.0f / L[l];
        u32 xf = __float2uint_rn(X * XSCALE);
        xq[l] = (u16)(xf > 65535u ? 65535u : xf);
        out_links[3 * l + 0] = Lq;
        out_links[3 * l + 1] = rho;
        out_links[3 * l + 2] = pi0 * r32;
    }
}

// ---------------------------------------------------------------------------
// gather: X_l table in LDS (Q17 u16); integer per-path sum, 4 paths/thread.
// ---------------------------------------------------------------------------
__global__ __launch_bounds__(BS) void gather_kernel(
        const u16* __restrict__ e16,
        const u16* __restrict__ xq,          // 16B-aligned
        float*     __restrict__ res,
        int n_paths, int n_links) {
    __shared__ u16 xl[MAXL];
    const int tid = threadIdx.x;
    const int nx8 = n_links >> 3;            // 8 u16 per uint4
    for (int i = tid; i < nx8; i += BS)
        ((uint4*)xl)[i] = ((const uint4*)xq)[i];
    for (int i = (nx8 << 3) + tid; i < n_links; i += BS) xl[i] = xq[i];
    __syncthreads();

    const int nthreads = gridDim.x * BS;
    for (int p = (blockIdx.x * BS + tid) * 4; p < n_paths; p += 4 * nthreads) {
        u32 s0 = 0, s1 = 0, s2 = 0, s3 = 0;
#pragma unroll
        for (int k = 0; k < KHOPS; ++k) {
            uint2 ep = *(const uint2*)&e16[k * n_paths + p];
            s0 += xl[ep.x & 0xffffu];
            s1 += xl[ep.x >> 16];
            s2 += xl[ep.y & 0xffffu];
            s3 += xl[ep.y >> 16];
        }
        *(float4*)&res[p] = make_float4((float)s0 * (1.0f / XSCALE),
                                        (float)s1 * (1.0f / XSCALE),
                                        (float)s2 * (1.0f / XSCALE),
                                        (float)s3 * (1.0f / XSCALE));
    }
}

// ---------------------------------------------------------------------------
extern "C" void kernel_launch(void* const* d_in, const int* in_sizes, int n_in,
                              void* d_out, int out_size, void* d_ws, size_t ws_size,
                              hipStream_t stream) {
    const float* P        = (const float*)d_in[0];   // (n_paths, 3)
    const float* L        = (const float*)d_in[1];   // (n_links, 1)
    const int*   pl_edges = (const int*)d_in[3];     // (KHOPS, n_paths)

    const int n_paths = in_sizes[0] / 3;
    const int n_links = in_sizes[1];
    const int n_edges = KHOPS * n_paths;
    const int nwords  = (n_links + 1) / 2;

    // ws layout: e16 | A | bpq(u8) | xq(u16) | partial (u32 NXCD*nl) | Trep
    char* w = (char*)d_ws;
    u16*   e16 = (u16*)w;                     w += (size_t)n_edges * 2;
    w = (char*)(((size_t)w + 15) & ~15ull);
    float* A   = (float*)w;                   w += (size_t)n_paths * 4;
    u8*    bpq = (u8*)w;                      w += (size_t)n_links;
    w = (char*)(((size_t)w + 15) & ~15ull);
    u16*   xq  = (u16*)w;                     w += (size_t)n_links * 2;
    w = (char*)(((size_t)w + 15) & ~15ull);
    u32* partial = (u32*)w;                   w += (size_t)NXCD * n_links * 4;
    u32* Trep    = (u32*)w;                   // GRID*nwords*4 = 25.6 MB

    float* res       = (float*)d_out;                // (n_paths,)
    float* out_links = res + n_paths;                // (n_links, 3)

    const int bs = 256;
    const int gl = (n_links + bs - 1) / bs;
    const int npairs = nwords >> 1;
    const int gm = NXCD * ((npairs + BS - 1) / BS);  // XCD-aligned merge grid

    for (int it = 0; it < 3; ++it) {
        if (it == 0)
            scatter_first<<<GRID, BS, 0, stream>>>(P, pl_edges, e16, A, Trep,
                                                   n_paths, nwords);
        else
            scatter_rest<<<GRID, BS, 0, stream>>>(A, e16, bpq, Trep,
                                                  n_paths, n_links, nwords);
        merge_kernel<<<gm, BS, 0, stream>>>(Trep, partial, n_links, nwords);
        link_update_kernel<<<gl, bs, 0, stream>>>(L, partial, bpq, xq,
                                                  out_links, n_links,
                                                  it == 2 ? 1 : 0);
    }
    gather_kernel<<<GRID, BS, 0, stream>>>(e16, xq, res, n_paths, n_links);
}